// Round 14
// baseline (205.921 us; speedup 1.0000x reference)
//
#include <hip/hip_runtime.h>
#include <hip/hip_fp16.h>
#include <math.h>

#define NB 8
#define NCLS 8
#define NGU 6
#define NBI 14
#define HF 512
#define WF 512
#define HH 256
#define WH 256

// MFMA mean-field tile: 32x16 output, 36x20 staged halo
#define TOX 32
#define TOY 16
#define SX 36
#define SY 20
#define SPX (SY * SX)     // 720 staged px
#define R1W 36
#define R1N (18 * 36)     // iter1 region: rows 1..18 x cols 0..35 = 648 px
#define R1T 41            // ceil(648/16)
#define R2T 32
// LDS tile: two planes of [px][8ch] fp16 with zero guards between
#define PLANE (SPX * 8)       // 5760 halves
#define PSTR (PLANE + 32)     // 5792 halves plane stride (guard in between)
#define TILEH (16 + PSTR + PLANE + 16)  // 11584 halves total

typedef _Float16 f16x8 __attribute__((ext_vector_type(8)));
typedef float f32x4 __attribute__((ext_vector_type(4)));

static __device__ __forceinline__ void ac_prep(int o, float scale, int insz,
                                               int& i0, int& i1, float& f) {
    float s = (float)o * scale;
    int ii = (int)floorf(s);
    if (ii > insz - 1) ii = insz - 1;
    if (ii < 0) ii = 0;
    i0 = ii;
    i1 = (ii + 1 < insz) ? (ii + 1) : (insz - 1);
    f = s - (float)ii;
}

// async global->LDS, 16B per lane; LDS base wave-uniform (HW adds lane*16)
static __device__ __forceinline__ void dma16(const _Float16* g, _Float16* l) {
    __builtin_amdgcn_global_load_lds(
        (const __attribute__((address_space(1))) void*)g,
        (__attribute__((address_space(3))) void*)l, 16, 0, 0);
}
static __device__ __forceinline__ void dma16f(const float* g, float* l) {
    __builtin_amdgcn_global_load_lds(
        (const __attribute__((address_space(1))) void*)g,
        (__attribute__((address_space(3))) void*)l, 16, 0, 0);
}

// ---------------- K_init: fold compat + build MFMA B-fragments (1 block) ----------------
__global__ void k_prep_wf(const float* __restrict__ wsp, const float* __restrict__ wbil,
                          const float* __restrict__ cw, _Float16* __restrict__ wf) {
    __shared__ float sW2[NBI * 72];
    int tid = threadIdx.x;
    if (tid < NBI * 72) {
        int o = tid & 7;
        int t = (tid >> 3) % 9;
        int ci = tid / 72;
        float s = 0.f;
        for (int c = 0; c < NCLS; ++c)
            s += cw[o * NCLS + c] * wbil[((size_t)c * NBI + ci) * 9 + t];
        if (ci < NCLS) s += cw[o * NCLS + ci] * wsp[ci * 9 + t];
        sW2[tid] = s;
    }
    __syncthreads();
    if (tid < 5 * 64) {
        int l = tid & 63;
        int col = l & 15, kg = l >> 4;
        #pragma unroll
        for (int e = 0; e < 8; ++e) {
            int k = (tid >> 6) * 32 + kg * 8 + e;
            int tap = k >> 4, ci = k & 15;
            float v = (tap < 9 && ci < 14 && col < 8) ? sW2[ci * 72 + tap * 8 + col] : 0.f;
            wf[tid * 8 + e] = (_Float16)v;
        }
    }
}

// ---------------- skip projection: small-tile LDS-DMA staging ----------------
// Block owns 256 contiguous px, loops 16-channel groups: stage [16][256] fp32
// (16 x 1KB wave-DMAs) -> barrier -> accumulate. 22.5KB LDS -> ~7 blocks/CU, so
// one block's barrier drain overlaps other blocks' DMA issue (m114 mechanism).
template <int C, int HW>
static __device__ __forceinline__ void skip_run16(
    const float* __restrict__ feat, const float* __restrict__ wg,
    const float* __restrict__ bg, float* __restrict__ out, int idx,
    float* st, float* sw, int tid, int lane, int wv) {
    for (int i = tid; i < 3 * C; i += 256) sw[i] = wg[i];
    const int pxg = idx * 256;
    const int n = pxg / HW;
    const int hw0 = pxg - n * HW;
    const float* fb = feat + (size_t)n * C * HW + hw0;
    float a0 = 0.f, a1 = 0.f, a2 = 0.f;
    for (int g = 0; g < C; g += 16) {
        #pragma unroll
        for (int r = 0; r < 4; ++r)
            dma16f(fb + (size_t)(g + wv + 4 * r) * HW + lane * 4,
                   st + (wv + 4 * r) * 256);
        __syncthreads();   // drains vmcnt -> tile ready (overlap via other blocks)
        #pragma unroll
        for (int c = 0; c < 16; ++c) {
            const float v = st[c * 256 + tid];
            a0 = fmaf(sw[g + c], v, a0);
            a1 = fmaf(sw[C + g + c], v, a1);
            a2 = fmaf(sw[2 * C + g + c], v, a2);
        }
        __syncthreads();   // protect tile before next stage
    }
    float* op = out + (size_t)n * 3 * HW + hw0 + tid;
    op[0] = bg[0] + a0;
    op[HW] = bg[1] + a1;
    op[2 * (size_t)HW] = bg[2] + a2;
}

// bid [0,32): L3  [32,160): L2  [160,672): L1  [672,2720): L0  (heavy first)
__global__ __launch_bounds__(256) void k_skip_all(
    const float* __restrict__ s0, const float* __restrict__ s1,
    const float* __restrict__ s2, const float* __restrict__ s3,
    const float* __restrict__ w0, const float* __restrict__ w1,
    const float* __restrict__ w2, const float* __restrict__ w3,
    const float* __restrict__ b0, const float* __restrict__ b1,
    const float* __restrict__ b2, const float* __restrict__ b3,
    float* __restrict__ p0, float* __restrict__ p1,
    float* __restrict__ p2, float* __restrict__ p3) {
    __shared__ __align__(16) float st[16 * 256];  // 16 KB stage
    __shared__ float sw[3 * 512];                 // 6 KB weights
    const int bid = blockIdx.x;
    const int tid = threadIdx.x;
    const int lane = tid & 63;
    const int wv = tid >> 6;
    if (bid < 32)
        skip_run16<512, 1024>(s3, w3, b3, p3, bid, st, sw, tid, lane, wv);
    else if (bid < 160)
        skip_run16<256, 4096>(s2, w2, b2, p2, bid - 32, st, sw, tid, lane, wv);
    else if (bid < 672)
        skip_run16<128, 16384>(s1, w1, b1, p1, bid - 160, st, sw, tid, lane, wv);
    else
        skip_run16<64, 65536>(s0, w0, b0, p0, bid - 672, st, sw, tid, lane, wv);
}

// ---------------- K2: build packed fp16 NHWC guidance + Q0 (2 px/thread) ----------------
__global__ void k_prep_full(const float* __restrict__ logits, const float* __restrict__ image,
                            const float* __restrict__ p0, const float* __restrict__ p1,
                            const float* __restrict__ p2, const float* __restrict__ p3,
                            _Float16* __restrict__ Gh, _Float16* __restrict__ Q0h) {
    const int HW = HF * WF;
    int t = blockIdx.x * blockDim.x + threadIdx.x;
    if (t >= NB * HW / 2) return;
    int idx = t * 2;
    int n = idx / HW, r = idx - n * HW;
    int y = r / WF, x = r - y * WF;

    const float* ps[4] = {p0, p1, p2, p3};
    const int ss[4] = {256, 128, 64, 32};
    float f[2][3] = {{0.f, 0.f, 0.f}, {0.f, 0.f, 0.f}};
    #pragma unroll
    for (int l = 0; l < 4; ++l) {
        int s = ss[l];
        float scale = (float)(s - 1) / 511.0f;
        int y0, y1;
        float fy;
        ac_prep(y, scale, s, y0, y1, fy);
        const float* pb = ps[l] + (size_t)n * 3 * s * s;
        #pragma unroll
        for (int k = 0; k < 2; ++k) {
            int x0, x1;
            float fx;
            ac_prep(x + k, scale, s, x0, x1, fx);
            #pragma unroll
            for (int o = 0; o < 3; ++o) {
                const float* pp = pb + (size_t)o * s * s;
                float v00 = pp[y0 * s + x0], v01 = pp[y0 * s + x1];
                float v10 = pp[y1 * s + x0], v11 = pp[y1 * s + x1];
                float r0 = v00 * (1.f - fy) + v10 * fy;
                float r1 = v01 * (1.f - fy) + v11 * fy;
                f[k][o] += r0 * (1.f - fx) + r1 * fx;
            }
        }
    }
    const float* ip = image + (size_t)n * 3 * HW + r;
    float2 img[3];
    #pragma unroll
    for (int o = 0; o < 3; ++o) img[o] = *reinterpret_cast<const float2*>(&ip[(size_t)o * HW]);
    const float* up = logits + (size_t)n * NCLS * HW + r;
    float2 u[8];
    #pragma unroll
    for (int o = 0; o < 8; ++o) u[o] = *reinterpret_cast<const float2*>(&up[(size_t)o * HW]);

    f16x8 gv[2], qv[2];
    #pragma unroll
    for (int k = 0; k < 2; ++k) {
        gv[k][0] = (_Float16)(k ? img[0].y : img[0].x);
        gv[k][1] = (_Float16)(k ? img[1].y : img[1].x);
        gv[k][2] = (_Float16)(k ? img[2].y : img[2].x);
        gv[k][3] = (_Float16)(f[k][0] * 0.25f);
        gv[k][4] = (_Float16)(f[k][1] * 0.25f);
        gv[k][5] = (_Float16)(f[k][2] * 0.25f);
        gv[k][6] = (_Float16)0.f;
        gv[k][7] = (_Float16)0.f;
        float e[8];
        float s = 0.f;
        #pragma unroll
        for (int o = 0; o < 8; ++o) { e[o] = __expf(k ? u[o].y : u[o].x); s += e[o]; }
        float inv = 1.f / s;
        #pragma unroll
        for (int o = 0; o < 8; ++o) qv[k][o] = (_Float16)(e[o] * inv);
    }
    *(f16x8*)(Gh + (size_t)idx * 8) = gv[0];
    *(f16x8*)(Gh + (size_t)idx * 8 + 8) = gv[1];
    *(f16x8*)(Q0h + (size_t)idx * 8) = qv[0];
    *(f16x8*)(Q0h + (size_t)idx * 8 + 8) = qv[1];
}

// ---------------- K5: both mean-field iterations, conv on MFMA ----------------
template <bool DOWN, bool UPFOLD>
__global__ __launch_bounds__(256, 4) void k_mf_mfma(
    const float* __restrict__ unary, const _Float16* __restrict__ Q0h,
    const _Float16* __restrict__ Gh, const _Float16* __restrict__ Qd,
    void* __restrict__ QoutV, const _Float16* __restrict__ wfragG,
    int H, int W, int Hs, int Ws) {
    __shared__ __align__(16) _Float16 s_t[TILEH];
    __shared__ __align__(16) _Float16 s_msg[R1N * 8];
    _Float16* tb0 = s_t + 16;            // Q plane (ci 0..7)
    _Float16* tb1 = s_t + 16 + PSTR;     // guid plane (ci 8..15)

    const int tid = threadIdx.x;
    const int lane = tid & 63;
    const int wv = tid >> 6;
    const int n = blockIdx.z;
    const int gx0 = blockIdx.x * TOX;
    const int gy0 = blockIdx.y * TOY;
    const int HW = H * W;
    const int HWs = Hs * Ws;

    // weight fragments (wave-uniform, L2-broadcast)
    f16x8 wf[5];
    #pragma unroll
    for (int j = 0; j < 5; ++j)
        wf[j] = *(const f16x8*)(wfragG + (j * 64 + lane) * 8);

    // zero guard pads: [0,16), [5776,5808), [11568,11584)
    if (tid < 16) s_t[tid] = (_Float16)0.f;
    else if (tid < 48) s_t[5760 + tid] = (_Float16)0.f;
    else if (tid < 64) s_t[11520 + tid] = (_Float16)0.f;

    const bool interior = !DOWN && gx0 >= 2 && (gx0 + TOX + 2) <= W &&
                          gy0 >= 2 && (gy0 + TOY + 2) <= H;

    if (!DOWN && interior) {
        // ---- fast staging: async DMA, 64 px per chunk, 12 chunks per plane ----
        const size_t nb = (size_t)n * HW;
        for (int c = wv; c < 12; c += 4) {
            int px = c * 64 + lane;
            int yy = px / SX, xx = px - yy * SX;
            size_t goff = (nb + (size_t)(gy0 + yy - 2) * W + (gx0 + xx - 2)) * 8;
            if (px < SPX) {
                dma16(Q0h + goff, tb0 + (size_t)c * 64 * 8);
                dma16(Gh + goff, tb1 + (size_t)c * 64 * 8);
            }
        }
    } else {
        const float syc = DOWN ? (float)(Hs - 1) / (float)(H - 1) : 1.f;
        const float sxc = DOWN ? (float)(Ws - 1) / (float)(W - 1) : 1.f;
        for (int i = tid; i < SPX; i += 256) {
            int yy = i / SX, xx = i - yy * SX;
            int gy = gy0 + yy - 2, gx = gx0 + xx - 2;
            f16x8 qv, gv;
            #pragma unroll
            for (int o = 0; o < 8; ++o) { qv[o] = (_Float16)0.f; gv[o] = (_Float16)0.f; }
            if ((unsigned)gy < (unsigned)H && (unsigned)gx < (unsigned)W) {
                if (DOWN) {
                    int y0, y1, x0, x1;
                    float fy, fx;
                    ac_prep(gy, syc, Hs, y0, y1, fy);
                    ac_prep(gx, sxc, Ws, x0, x1, fx);
                    const float w00 = (1.f - fy) * (1.f - fx), w01 = (1.f - fy) * fx;
                    const float w10 = fy * (1.f - fx), w11 = fy * fx;
                    const size_t o00 = (size_t)y0 * Ws + x0, o01 = (size_t)y0 * Ws + x1;
                    const size_t o10 = (size_t)y1 * Ws + x0, o11 = (size_t)y1 * Ws + x1;
                    const float* ubase = unary + (size_t)n * NCLS * HWs;
                    float e[8];
                    float s = 0.f;
                    #pragma unroll
                    for (int o = 0; o < 8; ++o) {
                        const float* up = ubase + (size_t)o * HWs;
                        float u = w00 * up[o00] + w01 * up[o01] + w10 * up[o10] + w11 * up[o11];
                        e[o] = __expf(u);
                        s += e[o];
                    }
                    float inv = 1.f / s;
                    #pragma unroll
                    for (int o = 0; o < 8; ++o) qv[o] = (_Float16)(e[o] * inv);
                    const size_t gb = (size_t)n * HWs;
                    f16x8 ga = *(const f16x8*)(Gh + (gb + o00) * 8);
                    f16x8 gb2 = *(const f16x8*)(Gh + (gb + o01) * 8);
                    f16x8 gc = *(const f16x8*)(Gh + (gb + o10) * 8);
                    f16x8 gd = *(const f16x8*)(Gh + (gb + o11) * 8);
                    #pragma unroll
                    for (int c = 0; c < 8; ++c) {
                        float g = w00 * (float)ga[c] + w01 * (float)gb2[c] +
                                  w10 * (float)gc[c] + w11 * (float)gd[c];
                        gv[c] = (_Float16)g;
                    }
                } else {
                    const size_t off = ((size_t)n * HW + (size_t)gy * W + gx) * 8;
                    qv = *(const f16x8*)(Q0h + off);
                    gv = *(const f16x8*)(Gh + off);
                }
            }
            *(f16x8*)(tb0 + i * 8) = qv;
            *(f16x8*)(tb1 + i * 8) = gv;
        }
    }
    __syncthreads();

    // ================= iteration 1 MFMA: rows 1..18 x cols 0..35 =================
    for (int t = wv; t < R1T; t += 4) {
        int pb = t * 16;
        int p = pb + (lane & 15);
        if (p > R1N - 1) p = R1N - 1;
        int qy = p / R1W;
        int yy = 1 + qy, xx = p - qy * R1W;
        int kg = lane >> 4;
        f32x4 acc = {0.f, 0.f, 0.f, 0.f};
        #pragma unroll
        for (int j = 0; j < 5; ++j) {
            int tap = 2 * j + (kg >> 1);
            if (tap > 8) tap = 8;
            int dy = tap / 3 - 1, dx = tap - (tap / 3) * 3 - 1;
            int idx = (yy + dy) * SX + (xx + dx);
            f16x8 af = *(const f16x8*)(tb0 + (kg & 1) * PSTR + idx * 8);
            acc = __builtin_amdgcn_mfma_f32_16x16x32_f16(af, wf[j], acc, 0, 0, 0);
        }
        int ch = lane & 15;
        if (ch < 8) {
            int pxb = pb + (lane >> 4) * 4;
            #pragma unroll
            for (int r = 0; r < 4; ++r) {
                int px = pxb + r;
                if (px < R1N) s_msg[px * 8 + ch] = (_Float16)acc[r];
            }
        }
    }
    __syncthreads();

    // ---- epilogue 1: Q1 = norm(Q0 * exp(-m1)) in-place in Q plane ----
    for (int i = tid; i < R1N; i += 256) {
        int qy = i / R1W;
        int yy = 1 + qy, xx = i - qy * R1W;
        int gy = gy0 + yy - 2, gx = gx0 + xx - 2;
        if (interior || ((unsigned)gy < (unsigned)H && (unsigned)gx < (unsigned)W)) {
            f16x8 m = *(const f16x8*)(s_msg + i * 8);
            f16x8 q0 = *(const f16x8*)(tb0 + (i + SX) * 8);
            float e[8];
            float s = 0.f;
            #pragma unroll
            for (int o = 0; o < 8; ++o) {
                e[o] = (float)q0[o] * __expf(-(float)m[o]);
                s += e[o];
            }
            float inv = 1.f / s;
            f16x8 q1;
            #pragma unroll
            for (int o = 0; o < 8; ++o) q1[o] = (_Float16)(e[o] * inv);
            *(f16x8*)(tb0 + (i + SX) * 8) = q1;
        }
    }
    // capture m1 for this thread's two output px (s_msg still holds m1)
    f16x8 m1r[2];
    #pragma unroll
    for (int u2 = 0; u2 < 2; ++u2) {
        int i = tid + 256 * u2;
        int oy = i >> 5, ox = i & 31;
        int r1 = (1 + oy) * R1W + (2 + ox);
        m1r[u2] = *(const f16x8*)(s_msg + r1 * 8);
    }
    __syncthreads();

    // ================= iteration 2 MFMA: rows 2..17 x cols 2..33 =================
    for (int t = wv; t < R2T; t += 4) {
        int pb = t * 16;
        int p = pb + (lane & 15);
        int yy = 2 + (p >> 5), xx = 2 + (p & 31);
        int kg = lane >> 4;
        f32x4 acc = {0.f, 0.f, 0.f, 0.f};
        #pragma unroll
        for (int j = 0; j < 5; ++j) {
            int tap = 2 * j + (kg >> 1);
            if (tap > 8) tap = 8;
            int dy = tap / 3 - 1, dx = tap - (tap / 3) * 3 - 1;
            int idx = (yy + dy) * SX + (xx + dx);
            f16x8 af = *(const f16x8*)(tb0 + (kg & 1) * PSTR + idx * 8);
            acc = __builtin_amdgcn_mfma_f32_16x16x32_f16(af, wf[j], acc, 0, 0, 0);
        }
        int ch = lane & 15;
        if (ch < 8) {
            int pxb = pb + (lane >> 4) * 4;
            #pragma unroll
            for (int r = 0; r < 4; ++r) s_msg[(pxb + r) * 8 + ch] = (_Float16)acc[r];
        }
    }
    __syncthreads();

    // ---- epilogue 2: Q2 = norm(Q1 * exp(m1 - m2)); write ----
    #pragma unroll
    for (int u2 = 0; u2 < 2; ++u2) {
        int i = tid + 256 * u2;
        int oy = i >> 5, ox = i & 31;
        int gy = gy0 + oy, gx = gx0 + ox;
        f16x8 m2 = *(const f16x8*)(s_msg + i * 8);
        f16x8 q1 = *(const f16x8*)(tb0 + ((2 + oy) * SX + (2 + ox)) * 8);
        float e[8];
        float s = 0.f;
        #pragma unroll
        for (int o = 0; o < 8; ++o) {
            e[o] = (float)q1[o] * __expf((float)m1r[u2][o] - (float)m2[o]);
            s += e[o];
        }
        float inv = 1.f / s;
        if (UPFOLD) {
            float* qp = (float*)QoutV + (size_t)n * NCLS * HW + (size_t)gy * W + gx;
            int y0, y1, x0, x1;
            float fy, fx;
            ac_prep(gy, 255.f / 511.f, HH, y0, y1, fy);
            ac_prep(gx, 255.f / 511.f, WH, x0, x1, fx);
            const float w00 = (1.f - fy) * (1.f - fx), w01 = (1.f - fy) * fx;
            const float w10 = fy * (1.f - fx), w11 = fy * fx;
            const size_t qb = (size_t)n * (HH * WH);
            f16x8 qa = *(const f16x8*)(Qd + (qb + (size_t)y0 * WH + x0) * 8);
            f16x8 qbv = *(const f16x8*)(Qd + (qb + (size_t)y0 * WH + x1) * 8);
            f16x8 qc = *(const f16x8*)(Qd + (qb + (size_t)y1 * WH + x0) * 8);
            f16x8 qdv = *(const f16x8*)(Qd + (qb + (size_t)y1 * WH + x1) * 8);
            #pragma unroll
            for (int o = 0; o < 8; ++o) {
                float v = w00 * (float)qa[o] + w01 * (float)qbv[o] +
                          w10 * (float)qc[o] + w11 * (float)qdv[o];
                qp[(size_t)o * HW] = fmaf(0.5f, e[o] * inv, 0.5f * v);
            }
        } else {
            _Float16* qo = (_Float16*)QoutV + ((size_t)n * HW + (size_t)gy * W + gx) * 8;
            f16x8 q2;
            #pragma unroll
            for (int o = 0; o < 8; ++o) q2[o] = (_Float16)(e[o] * inv);
            *(f16x8*)qo = q2;
        }
    }
}

static inline int cdiv(int a, int b) { return (a + b - 1) / b; }

extern "C" void kernel_launch(void* const* d_in, const int* in_sizes, int n_in,
                              void* d_out, int out_size, void* d_ws, size_t ws_size,
                              hipStream_t stream) {
    const float* logits = (const float*)d_in[0];
    const float* image = (const float*)d_in[1];
    const float* skip0 = (const float*)d_in[2];
    const float* skip1 = (const float*)d_in[3];
    const float* skip2 = (const float*)d_in[4];
    const float* skip3 = (const float*)d_in[5];
    const float* spatial_w = (const float*)d_in[6];
    const float* bilateral_w = (const float*)d_in[7];
    const float* compat_w = (const float*)d_in[8];
    const float* skip_w0 = (const float*)d_in[9];
    const float* skip_b0 = (const float*)d_in[10];
    const float* skip_w1 = (const float*)d_in[11];
    const float* skip_b1 = (const float*)d_in[12];
    const float* skip_w2 = (const float*)d_in[13];
    const float* skip_b2 = (const float*)d_in[14];
    const float* skip_w3 = (const float*)d_in[15];
    const float* skip_b3 = (const float*)d_in[16];
    float* out = (float*)d_out;
    float* ws = (float*)d_ws;

    // workspace layout (float offsets):
    float* p0 = ws + 0;                    // 1,572,864
    float* p1 = ws + 1572864;              // 393,216
    float* p2 = ws + 1966080;              // 98,304
    float* p3 = ws + 2064384;              // 24,576
    _Float16* wfrag = (_Float16*)(ws + 2110000);   // 2560 halves
    _Float16* Q0h = (_Float16*)(ws + 4194304);     // 8,388,608 floats
    _Float16* Gh = (_Float16*)(ws + 12582912);     // 8,388,608 floats
    _Float16* Qdh = (_Float16*)(ws + 20971520);    // 2,097,152 floats

    const int HWf = HF * WF;

    // --- weight prep (1 block) ---
    k_prep_wf<<<1, 1024, 0, stream>>>(spatial_w, bilateral_w, compat_w, wfrag);

    // --- all skip projections: small-tile LDS-DMA, atomic-free, bias folded ---
    k_skip_all<<<2720, 256, 0, stream>>>(skip0, skip1, skip2, skip3,
                                         skip_w0, skip_w1, skip_w2, skip_w3,
                                         skip_b0, skip_b1, skip_b2, skip_b3,
                                         p0, p1, p2, p3);

    // --- packed guidance + Q0 (fp16 NHWC, 2 px/thread) ---
    k_prep_full<<<cdiv(NB * HWf / 2, 256), 256, 0, stream>>>(
        logits, image, p0, p1, p2, p3, Gh, Q0h);

    // --- half-res mean field: gathers from full-res logits + Gh ---
    {
        dim3 grid(WH / TOX, HH / TOY, NB);
        k_mf_mfma<true, false><<<grid, 256, 0, stream>>>(
            logits, nullptr, Gh, nullptr, (void*)Qdh, wfrag, HH, WH, HF, WF);
    }

    // --- full-res mean field; epilogue folds in 0.5*upsample(Qdh) ---
    {
        dim3 grid(WF / TOX, HF / TOY, NB);
        k_mf_mfma<false, true><<<grid, 256, 0, stream>>>(
            nullptr, Q0h, Gh, Qdh, (void*)out, wfrag, HF, WF, HF, WF);
    }
}

// Round 15
// 190.510 us; speedup vs baseline: 1.0809x; 1.0809x over previous
//
#include <hip/hip_runtime.h>
#include <hip/hip_fp16.h>
#include <math.h>

#define NB 8
#define NCLS 8
#define NGU 6
#define NBI 14
#define HF 512
#define WF 512
#define HH 256
#define WH 256

// MFMA mean-field tile: 32x16 output, 36x20 staged halo
#define TOX 32
#define TOY 16
#define SX 36
#define SY 20
#define SPX (SY * SX)     // 720 staged px
#define R1W 36
#define R1N (18 * 36)     // iter1 region: rows 1..18 x cols 0..35 = 648 px
#define R1T 41            // ceil(648/16)
#define R2T 32
// LDS tile: two planes of [px][8ch] fp16 with zero guards between
#define PLANE (SPX * 8)       // 5760 halves
#define PSTR (PLANE + 32)     // 5792 halves plane stride (guard in between)
#define TILEH (16 + PSTR + PLANE + 16)  // 11584 halves total

typedef _Float16 f16x8 __attribute__((ext_vector_type(8)));
typedef float f32x4 __attribute__((ext_vector_type(4)));

static __device__ __forceinline__ void ac_prep(int o, float scale, int insz,
                                               int& i0, int& i1, float& f) {
    float s = (float)o * scale;
    int ii = (int)floorf(s);
    if (ii > insz - 1) ii = insz - 1;
    if (ii < 0) ii = 0;
    i0 = ii;
    i1 = (ii + 1 < insz) ? (ii + 1) : (insz - 1);
    f = s - (float)ii;
}

// async global->LDS, 16B per lane; LDS base wave-uniform (HW adds lane*16)
static __device__ __forceinline__ void dma16(const _Float16* g, _Float16* l) {
    __builtin_amdgcn_global_load_lds(
        (const __attribute__((address_space(1))) void*)g,
        (__attribute__((address_space(3))) void*)l, 16, 0, 0);
}

// ---------------- K_init: fold compat + build MFMA B-fragments (1 block) ----------------
__global__ void k_prep_wf(const float* __restrict__ wsp, const float* __restrict__ wbil,
                          const float* __restrict__ cw, _Float16* __restrict__ wf) {
    __shared__ float sW2[NBI * 72];
    int tid = threadIdx.x;
    if (tid < NBI * 72) {
        int o = tid & 7;
        int t = (tid >> 3) % 9;
        int ci = tid / 72;
        float s = 0.f;
        for (int c = 0; c < NCLS; ++c)
            s += cw[o * NCLS + c] * wbil[((size_t)c * NBI + ci) * 9 + t];
        if (ci < NCLS) s += cw[o * NCLS + ci] * wsp[ci * 9 + t];
        sW2[tid] = s;
    }
    __syncthreads();
    if (tid < 5 * 64) {
        int l = tid & 63;
        int col = l & 15, kg = l >> 4;
        #pragma unroll
        for (int e = 0; e < 8; ++e) {
            int k = (tid >> 6) * 32 + kg * 8 + e;
            int tap = k >> 4, ci = k & 15;
            float v = (tap < 9 && ci < 14 && col < 8) ? sW2[ci * 72 + tap * 8 + col] : 0.f;
            wf[tid * 8 + e] = (_Float16)v;
        }
    }
}

// ---------------- skip projection: C-reduction parallelized across threads ----------------
// Thread = (slice, pxg): 8 channels x one float4 pixel-group. 8 INDEPENDENT loads
// issued once (no serial channel loop), 24 FMA, LDS tree-reduce over slices.
// All levels fit C in one block -> direct store with bias, zero atomics.
template <int C, int HW, int SLICES, int PXG>
static __device__ __forceinline__ void skip_gemm(
    const float* __restrict__ feat, const float* __restrict__ wg,
    const float* __restrict__ bg, float* __restrict__ out, int bidl,
    float* sw, f32x4* sred, int tid) {
    for (int i = tid; i < 3 * C; i += 256) sw[i] = wg[i];
    __syncthreads();
    const int slice = tid / PXG;
    const int pxg = tid - slice * PXG;
    const int pxbase = bidl * (PXG * 4);
    const int n = pxbase / HW;
    const int hw0 = pxbase - n * HW;
    const float* fp = feat + ((size_t)n * C + slice * 8) * HW + hw0 + pxg * 4;

    f32x4 v[8];
    #pragma unroll
    for (int j = 0; j < 8; ++j)
        v[j] = *reinterpret_cast<const f32x4*>(fp + (size_t)j * HW);

    f32x4 a0 = {0.f, 0.f, 0.f, 0.f};
    f32x4 a1 = {0.f, 0.f, 0.f, 0.f};
    f32x4 a2 = {0.f, 0.f, 0.f, 0.f};
    #pragma unroll
    for (int j = 0; j < 8; ++j) {
        const int c = slice * 8 + j;
        a0 += v[j] * sw[c];
        a1 += v[j] * sw[C + c];
        a2 += v[j] * sw[2 * C + c];
    }
    sred[0 * 256 + tid] = a0;
    sred[1 * 256 + tid] = a1;
    sred[2 * 256 + tid] = a2;
    __syncthreads();
    // tree-fold 256 -> 2*PXG entries
    for (int s = 128; s > PXG; s >>= 1) {
        if (tid < s) {
            sred[tid] += sred[tid + s];
            sred[256 + tid] += sred[256 + tid + s];
            sred[512 + tid] += sred[512 + tid + s];
        }
        __syncthreads();
    }
    if (tid < PXG) {
        float* op = out + (size_t)n * 3 * HW + hw0 + tid * 4;
        f32x4 r0 = sred[tid] + sred[tid + PXG] + bg[0];
        f32x4 r1 = sred[256 + tid] + sred[256 + tid + PXG] + bg[1];
        f32x4 r2 = sred[512 + tid] + sred[512 + tid + PXG] + bg[2];
        *reinterpret_cast<f32x4*>(op) = r0;
        *reinterpret_cast<f32x4*>(op + HW) = r1;
        *reinterpret_cast<f32x4*>(op + 2 * (size_t)HW) = r2;
    }
}

// bid [0,4096): L0  [4096,6144): L1  [6144,7168): L2  [7168,7680): L3
__global__ __launch_bounds__(256) void k_skip_all(
    const float* __restrict__ s0, const float* __restrict__ s1,
    const float* __restrict__ s2, const float* __restrict__ s3,
    const float* __restrict__ w0, const float* __restrict__ w1,
    const float* __restrict__ w2, const float* __restrict__ w3,
    const float* __restrict__ b0, const float* __restrict__ b1,
    const float* __restrict__ b2, const float* __restrict__ b3,
    float* __restrict__ p0, float* __restrict__ p1,
    float* __restrict__ p2, float* __restrict__ p3) {
    __shared__ __align__(16) f32x4 sred[3 * 256];  // 12 KB
    __shared__ float sw[3 * 512];                  // 6 KB
    const int bid = blockIdx.x;
    const int tid = threadIdx.x;
    if (bid < 4096)
        skip_gemm<64, 65536, 8, 32>(s0, w0, b0, p0, bid, sw, sred, tid);
    else if (bid < 6144)
        skip_gemm<128, 16384, 16, 16>(s1, w1, b1, p1, bid - 4096, sw, sred, tid);
    else if (bid < 7168)
        skip_gemm<256, 4096, 32, 8>(s2, w2, b2, p2, bid - 6144, sw, sred, tid);
    else
        skip_gemm<512, 1024, 64, 4>(s3, w3, b3, p3, bid - 7168, sw, sred, tid);
}

// ---------------- K2: build packed fp16 NHWC guidance + Q0 (2 px/thread) ----------------
__global__ void k_prep_full(const float* __restrict__ logits, const float* __restrict__ image,
                            const float* __restrict__ p0, const float* __restrict__ p1,
                            const float* __restrict__ p2, const float* __restrict__ p3,
                            _Float16* __restrict__ Gh, _Float16* __restrict__ Q0h) {
    const int HW = HF * WF;
    int t = blockIdx.x * blockDim.x + threadIdx.x;
    if (t >= NB * HW / 2) return;
    int idx = t * 2;
    int n = idx / HW, r = idx - n * HW;
    int y = r / WF, x = r - y * WF;

    const float* ps[4] = {p0, p1, p2, p3};
    const int ss[4] = {256, 128, 64, 32};
    float f[2][3] = {{0.f, 0.f, 0.f}, {0.f, 0.f, 0.f}};
    #pragma unroll
    for (int l = 0; l < 4; ++l) {
        int s = ss[l];
        float scale = (float)(s - 1) / 511.0f;
        int y0, y1;
        float fy;
        ac_prep(y, scale, s, y0, y1, fy);
        const float* pb = ps[l] + (size_t)n * 3 * s * s;
        #pragma unroll
        for (int k = 0; k < 2; ++k) {
            int x0, x1;
            float fx;
            ac_prep(x + k, scale, s, x0, x1, fx);
            #pragma unroll
            for (int o = 0; o < 3; ++o) {
                const float* pp = pb + (size_t)o * s * s;
                float v00 = pp[y0 * s + x0], v01 = pp[y0 * s + x1];
                float v10 = pp[y1 * s + x0], v11 = pp[y1 * s + x1];
                float r0 = v00 * (1.f - fy) + v10 * fy;
                float r1 = v01 * (1.f - fy) + v11 * fy;
                f[k][o] += r0 * (1.f - fx) + r1 * fx;
            }
        }
    }
    const float* ip = image + (size_t)n * 3 * HW + r;
    float2 img[3];
    #pragma unroll
    for (int o = 0; o < 3; ++o) img[o] = *reinterpret_cast<const float2*>(&ip[(size_t)o * HW]);
    const float* up = logits + (size_t)n * NCLS * HW + r;
    float2 u[8];
    #pragma unroll
    for (int o = 0; o < 8; ++o) u[o] = *reinterpret_cast<const float2*>(&up[(size_t)o * HW]);

    f16x8 gv[2], qv[2];
    #pragma unroll
    for (int k = 0; k < 2; ++k) {
        gv[k][0] = (_Float16)(k ? img[0].y : img[0].x);
        gv[k][1] = (_Float16)(k ? img[1].y : img[1].x);
        gv[k][2] = (_Float16)(k ? img[2].y : img[2].x);
        gv[k][3] = (_Float16)(f[k][0] * 0.25f);
        gv[k][4] = (_Float16)(f[k][1] * 0.25f);
        gv[k][5] = (_Float16)(f[k][2] * 0.25f);
        gv[k][6] = (_Float16)0.f;
        gv[k][7] = (_Float16)0.f;
        float e[8];
        float s = 0.f;
        #pragma unroll
        for (int o = 0; o < 8; ++o) { e[o] = __expf(k ? u[o].y : u[o].x); s += e[o]; }
        float inv = 1.f / s;
        #pragma unroll
        for (int o = 0; o < 8; ++o) qv[k][o] = (_Float16)(e[o] * inv);
    }
    *(f16x8*)(Gh + (size_t)idx * 8) = gv[0];
    *(f16x8*)(Gh + (size_t)idx * 8 + 8) = gv[1];
    *(f16x8*)(Q0h + (size_t)idx * 8) = qv[0];
    *(f16x8*)(Q0h + (size_t)idx * 8 + 8) = qv[1];
}

// ---------------- K5: both mean-field iterations, conv on MFMA ----------------
template <bool DOWN, bool UPFOLD>
__global__ __launch_bounds__(256, 4) void k_mf_mfma(
    const float* __restrict__ unary, const _Float16* __restrict__ Q0h,
    const _Float16* __restrict__ Gh, const _Float16* __restrict__ Qd,
    void* __restrict__ QoutV, const _Float16* __restrict__ wfragG,
    int H, int W, int Hs, int Ws) {
    __shared__ __align__(16) _Float16 s_t[TILEH];
    __shared__ __align__(16) _Float16 s_msg[R1N * 8];
    _Float16* tb0 = s_t + 16;            // Q plane (ci 0..7)
    _Float16* tb1 = s_t + 16 + PSTR;     // guid plane (ci 8..15)

    const int tid = threadIdx.x;
    const int lane = tid & 63;
    const int wv = tid >> 6;
    const int n = blockIdx.z;
    const int gx0 = blockIdx.x * TOX;
    const int gy0 = blockIdx.y * TOY;
    const int HW = H * W;
    const int HWs = Hs * Ws;

    // weight fragments (wave-uniform, L2-broadcast)
    f16x8 wf[5];
    #pragma unroll
    for (int j = 0; j < 5; ++j)
        wf[j] = *(const f16x8*)(wfragG + (j * 64 + lane) * 8);

    // zero guard pads: [0,16), [5776,5808), [11568,11584)
    if (tid < 16) s_t[tid] = (_Float16)0.f;
    else if (tid < 48) s_t[5760 + tid] = (_Float16)0.f;
    else if (tid < 64) s_t[11520 + tid] = (_Float16)0.f;

    const bool interior = !DOWN && gx0 >= 2 && (gx0 + TOX + 2) <= W &&
                          gy0 >= 2 && (gy0 + TOY + 2) <= H;

    if (!DOWN && interior) {
        // ---- fast staging: async DMA, 64 px per chunk, 12 chunks per plane ----
        const size_t nb = (size_t)n * HW;
        for (int c = wv; c < 12; c += 4) {
            int px = c * 64 + lane;
            int yy = px / SX, xx = px - yy * SX;
            size_t goff = (nb + (size_t)(gy0 + yy - 2) * W + (gx0 + xx - 2)) * 8;
            if (px < SPX) {
                dma16(Q0h + goff, tb0 + (size_t)c * 64 * 8);
                dma16(Gh + goff, tb1 + (size_t)c * 64 * 8);
            }
        }
    } else {
        const float syc = DOWN ? (float)(Hs - 1) / (float)(H - 1) : 1.f;
        const float sxc = DOWN ? (float)(Ws - 1) / (float)(W - 1) : 1.f;
        for (int i = tid; i < SPX; i += 256) {
            int yy = i / SX, xx = i - yy * SX;
            int gy = gy0 + yy - 2, gx = gx0 + xx - 2;
            f16x8 qv, gv;
            #pragma unroll
            for (int o = 0; o < 8; ++o) { qv[o] = (_Float16)0.f; gv[o] = (_Float16)0.f; }
            if ((unsigned)gy < (unsigned)H && (unsigned)gx < (unsigned)W) {
                if (DOWN) {
                    int y0, y1, x0, x1;
                    float fy, fx;
                    ac_prep(gy, syc, Hs, y0, y1, fy);
                    ac_prep(gx, sxc, Ws, x0, x1, fx);
                    const float w00 = (1.f - fy) * (1.f - fx), w01 = (1.f - fy) * fx;
                    const float w10 = fy * (1.f - fx), w11 = fy * fx;
                    const size_t o00 = (size_t)y0 * Ws + x0, o01 = (size_t)y0 * Ws + x1;
                    const size_t o10 = (size_t)y1 * Ws + x0, o11 = (size_t)y1 * Ws + x1;
                    const float* ubase = unary + (size_t)n * NCLS * HWs;
                    float e[8];
                    float s = 0.f;
                    #pragma unroll
                    for (int o = 0; o < 8; ++o) {
                        const float* up = ubase + (size_t)o * HWs;
                        float u = w00 * up[o00] + w01 * up[o01] + w10 * up[o10] + w11 * up[o11];
                        e[o] = __expf(u);
                        s += e[o];
                    }
                    float inv = 1.f / s;
                    #pragma unroll
                    for (int o = 0; o < 8; ++o) qv[o] = (_Float16)(e[o] * inv);
                    const size_t gb = (size_t)n * HWs;
                    f16x8 ga = *(const f16x8*)(Gh + (gb + o00) * 8);
                    f16x8 gb2 = *(const f16x8*)(Gh + (gb + o01) * 8);
                    f16x8 gc = *(const f16x8*)(Gh + (gb + o10) * 8);
                    f16x8 gd = *(const f16x8*)(Gh + (gb + o11) * 8);
                    #pragma unroll
                    for (int c = 0; c < 8; ++c) {
                        float g = w00 * (float)ga[c] + w01 * (float)gb2[c] +
                                  w10 * (float)gc[c] + w11 * (float)gd[c];
                        gv[c] = (_Float16)g;
                    }
                } else {
                    const size_t off = ((size_t)n * HW + (size_t)gy * W + gx) * 8;
                    qv = *(const f16x8*)(Q0h + off);
                    gv = *(const f16x8*)(Gh + off);
                }
            }
            *(f16x8*)(tb0 + i * 8) = qv;
            *(f16x8*)(tb1 + i * 8) = gv;
        }
    }
    __syncthreads();

    // ================= iteration 1 MFMA: rows 1..18 x cols 0..35 =================
    for (int t = wv; t < R1T; t += 4) {
        int pb = t * 16;
        int p = pb + (lane & 15);
        if (p > R1N - 1) p = R1N - 1;
        int qy = p / R1W;
        int yy = 1 + qy, xx = p - qy * R1W;
        int kg = lane >> 4;
        f32x4 acc = {0.f, 0.f, 0.f, 0.f};
        #pragma unroll
        for (int j = 0; j < 5; ++j) {
            int tap = 2 * j + (kg >> 1);
            if (tap > 8) tap = 8;
            int dy = tap / 3 - 1, dx = tap - (tap / 3) * 3 - 1;
            int idx = (yy + dy) * SX + (xx + dx);
            f16x8 af = *(const f16x8*)(tb0 + (kg & 1) * PSTR + idx * 8);
            acc = __builtin_amdgcn_mfma_f32_16x16x32_f16(af, wf[j], acc, 0, 0, 0);
        }
        int ch = lane & 15;
        if (ch < 8) {
            int pxb = pb + (lane >> 4) * 4;
            #pragma unroll
            for (int r = 0; r < 4; ++r) {
                int px = pxb + r;
                if (px < R1N) s_msg[px * 8 + ch] = (_Float16)acc[r];
            }
        }
    }
    __syncthreads();

    // ---- epilogue 1: Q1 = norm(Q0 * exp(-m1)) in-place in Q plane ----
    for (int i = tid; i < R1N; i += 256) {
        int qy = i / R1W;
        int yy = 1 + qy, xx = i - qy * R1W;
        int gy = gy0 + yy - 2, gx = gx0 + xx - 2;
        if (interior || ((unsigned)gy < (unsigned)H && (unsigned)gx < (unsigned)W)) {
            f16x8 m = *(const f16x8*)(s_msg + i * 8);
            f16x8 q0 = *(const f16x8*)(tb0 + (i + SX) * 8);
            float e[8];
            float s = 0.f;
            #pragma unroll
            for (int o = 0; o < 8; ++o) {
                e[o] = (float)q0[o] * __expf(-(float)m[o]);
                s += e[o];
            }
            float inv = 1.f / s;
            f16x8 q1;
            #pragma unroll
            for (int o = 0; o < 8; ++o) q1[o] = (_Float16)(e[o] * inv);
            *(f16x8*)(tb0 + (i + SX) * 8) = q1;
        }
    }
    // capture m1 for this thread's two output px (s_msg still holds m1)
    f16x8 m1r[2];
    #pragma unroll
    for (int u2 = 0; u2 < 2; ++u2) {
        int i = tid + 256 * u2;
        int oy = i >> 5, ox = i & 31;
        int r1 = (1 + oy) * R1W + (2 + ox);
        m1r[u2] = *(const f16x8*)(s_msg + r1 * 8);
    }
    __syncthreads();

    // ================= iteration 2 MFMA: rows 2..17 x cols 2..33 =================
    for (int t = wv; t < R2T; t += 4) {
        int pb = t * 16;
        int p = pb + (lane & 15);
        int yy = 2 + (p >> 5), xx = 2 + (p & 31);
        int kg = lane >> 4;
        f32x4 acc = {0.f, 0.f, 0.f, 0.f};
        #pragma unroll
        for (int j = 0; j < 5; ++j) {
            int tap = 2 * j + (kg >> 1);
            if (tap > 8) tap = 8;
            int dy = tap / 3 - 1, dx = tap - (tap / 3) * 3 - 1;
            int idx = (yy + dy) * SX + (xx + dx);
            f16x8 af = *(const f16x8*)(tb0 + (kg & 1) * PSTR + idx * 8);
            acc = __builtin_amdgcn_mfma_f32_16x16x32_f16(af, wf[j], acc, 0, 0, 0);
        }
        int ch = lane & 15;
        if (ch < 8) {
            int pxb = pb + (lane >> 4) * 4;
            #pragma unroll
            for (int r = 0; r < 4; ++r) s_msg[(pxb + r) * 8 + ch] = (_Float16)acc[r];
        }
    }
    __syncthreads();

    // ---- epilogue 2: Q2 = norm(Q1 * exp(m1 - m2)); write ----
    #pragma unroll
    for (int u2 = 0; u2 < 2; ++u2) {
        int i = tid + 256 * u2;
        int oy = i >> 5, ox = i & 31;
        int gy = gy0 + oy, gx = gx0 + ox;
        f16x8 m2 = *(const f16x8*)(s_msg + i * 8);
        f16x8 q1 = *(const f16x8*)(tb0 + ((2 + oy) * SX + (2 + ox)) * 8);
        float e[8];
        float s = 0.f;
        #pragma unroll
        for (int o = 0; o < 8; ++o) {
            e[o] = (float)q1[o] * __expf((float)m1r[u2][o] - (float)m2[o]);
            s += e[o];
        }
        float inv = 1.f / s;
        if (UPFOLD) {
            float* qp = (float*)QoutV + (size_t)n * NCLS * HW + (size_t)gy * W + gx;
            int y0, y1, x0, x1;
            float fy, fx;
            ac_prep(gy, 255.f / 511.f, HH, y0, y1, fy);
            ac_prep(gx, 255.f / 511.f, WH, x0, x1, fx);
            const float w00 = (1.f - fy) * (1.f - fx), w01 = (1.f - fy) * fx;
            const float w10 = fy * (1.f - fx), w11 = fy * fx;
            const size_t qb = (size_t)n * (HH * WH);
            f16x8 qa = *(const f16x8*)(Qd + (qb + (size_t)y0 * WH + x0) * 8);
            f16x8 qbv = *(const f16x8*)(Qd + (qb + (size_t)y0 * WH + x1) * 8);
            f16x8 qc = *(const f16x8*)(Qd + (qb + (size_t)y1 * WH + x0) * 8);
            f16x8 qdv = *(const f16x8*)(Qd + (qb + (size_t)y1 * WH + x1) * 8);
            #pragma unroll
            for (int o = 0; o < 8; ++o) {
                float v = w00 * (float)qa[o] + w01 * (float)qbv[o] +
                          w10 * (float)qc[o] + w11 * (float)qdv[o];
                qp[(size_t)o * HW] = fmaf(0.5f, e[o] * inv, 0.5f * v);
            }
        } else {
            _Float16* qo = (_Float16*)QoutV + ((size_t)n * HW + (size_t)gy * W + gx) * 8;
            f16x8 q2;
            #pragma unroll
            for (int o = 0; o < 8; ++o) q2[o] = (_Float16)(e[o] * inv);
            *(f16x8*)qo = q2;
        }
    }
}

static inline int cdiv(int a, int b) { return (a + b - 1) / b; }

extern "C" void kernel_launch(void* const* d_in, const int* in_sizes, int n_in,
                              void* d_out, int out_size, void* d_ws, size_t ws_size,
                              hipStream_t stream) {
    const float* logits = (const float*)d_in[0];
    const float* image = (const float*)d_in[1];
    const float* skip0 = (const float*)d_in[2];
    const float* skip1 = (const float*)d_in[3];
    const float* skip2 = (const float*)d_in[4];
    const float* skip3 = (const float*)d_in[5];
    const float* spatial_w = (const float*)d_in[6];
    const float* bilateral_w = (const float*)d_in[7];
    const float* compat_w = (const float*)d_in[8];
    const float* skip_w0 = (const float*)d_in[9];
    const float* skip_b0 = (const float*)d_in[10];
    const float* skip_w1 = (const float*)d_in[11];
    const float* skip_b1 = (const float*)d_in[12];
    const float* skip_w2 = (const float*)d_in[13];
    const float* skip_b2 = (const float*)d_in[14];
    const float* skip_w3 = (const float*)d_in[15];
    const float* skip_b3 = (const float*)d_in[16];
    float* out = (float*)d_out;
    float* ws = (float*)d_ws;

    // workspace layout (float offsets):
    float* p0 = ws + 0;                    // 1,572,864
    float* p1 = ws + 1572864;              // 393,216
    float* p2 = ws + 1966080;              // 98,304
    float* p3 = ws + 2064384;              // 24,576
    _Float16* wfrag = (_Float16*)(ws + 2110000);   // 2560 halves
    _Float16* Q0h = (_Float16*)(ws + 4194304);     // 8,388,608 floats
    _Float16* Gh = (_Float16*)(ws + 12582912);     // 8,388,608 floats
    _Float16* Qdh = (_Float16*)(ws + 20971520);    // 2,097,152 floats

    const int HWf = HF * WF;

    // --- weight prep (1 block) ---
    k_prep_wf<<<1, 1024, 0, stream>>>(spatial_w, bilateral_w, compat_w, wfrag);

    // --- all skip projections: thread-parallel C-reduction, all-direct stores ---
    k_skip_all<<<7680, 256, 0, stream>>>(skip0, skip1, skip2, skip3,
                                         skip_w0, skip_w1, skip_w2, skip_w3,
                                         skip_b0, skip_b1, skip_b2, skip_b3,
                                         p0, p1, p2, p3);

    // --- packed guidance + Q0 (fp16 NHWC, 2 px/thread) ---
    k_prep_full<<<cdiv(NB * HWf / 2, 256), 256, 0, stream>>>(
        logits, image, p0, p1, p2, p3, Gh, Q0h);

    // --- half-res mean field: gathers from full-res logits + Gh ---
    {
        dim3 grid(WH / TOX, HH / TOY, NB);
        k_mf_mfma<true, false><<<grid, 256, 0, stream>>>(
            logits, nullptr, Gh, nullptr, (void*)Qdh, wfrag, HH, WH, HF, WF);
    }

    // --- full-res mean field; epilogue folds in 0.5*upsample(Qdh) ---
    {
        dim3 grid(WF / TOX, HF / TOY, NB);
        k_mf_mfma<false, true><<<grid, 256, 0, stream>>>(
            nullptr, Q0h, Gh, Qdh, (void*)out, wfrag, HF, WF, HF, WF);
    }
}